// Round 8
// baseline (799.168 us; speedup 1.0000x reference)
//
#include <hip/hip_runtime.h>
#include <stdint.h>

#define B_ 8
#define C_ 256
#define N_ 4096
#define M_ 4096
#define NT 64
#define MT 64
#define L2E 1.44269504f

typedef _Float16 f16x8 __attribute__((ext_vector_type(8)));
typedef _Float16 f16x4 __attribute__((ext_vector_type(4)));
typedef _Float16 f16x2 __attribute__((ext_vector_type(2)));
typedef float f32x16 __attribute__((ext_vector_type(16)));
typedef unsigned int u32x4 __attribute__((ext_vector_type(4)));

// permlane32_swap: a' = [a_lo, b_lo], b' = [a_hi, b_hi]
__device__ __forceinline__ void plswap(unsigned &a, unsigned &b) {
    auto r = __builtin_amdgcn_permlane32_swap(a, b, false, false);
    a = r[0];
    b = r[1];
}

// fused pre-pass: blocks [0,2048) transpose xs -> kt [B,M,C] fp16;
//                 blocks [2048,10240) convert ys -> vb [B,C,M] fp16
__global__ __launch_bounds__(256) void kPre(const float* __restrict__ xs,
                                            const float* __restrict__ ys,
                                            _Float16* __restrict__ kt,
                                            _Float16* __restrict__ vb) {
    int bx = blockIdx.x;
    int t = threadIdx.x;
    if (bx < 2048) {
        __shared__ float tile[64][65];
        int b = bx >> 8, rem = bx & 255;
        int c0 = (rem >> 6) * 64, m0 = (rem & 63) * 64;
        int cl = t >> 4, m4 = (t & 15) * 4;
#pragma unroll
        for (int i = 0; i < 4; i++) {
            int c = c0 + cl + i * 16;
            const float4 v = *(const float4*)(xs + ((size_t)(b * C_ + c) * M_) + m0 + m4);
            tile[m4 + 0][cl + i * 16] = v.x;
            tile[m4 + 1][cl + i * 16] = v.y;
            tile[m4 + 2][cl + i * 16] = v.z;
            tile[m4 + 3][cl + i * 16] = v.w;
        }
        __syncthreads();
        int ml = t >> 4, c4 = (t & 15) * 4;
#pragma unroll
        for (int i = 0; i < 4; i++) {
            int m = m0 + ml + i * 16;
            f16x4 o;
            o[0] = (_Float16)tile[ml + i * 16][c4 + 0];
            o[1] = (_Float16)tile[ml + i * 16][c4 + 1];
            o[2] = (_Float16)tile[ml + i * 16][c4 + 2];
            o[3] = (_Float16)tile[ml + i * 16][c4 + 3];
            *(f16x4*)(kt + ((size_t)(b * M_ + m) * C_) + c0 + c4) = o;
        }
    } else {
        size_t i = ((size_t)(bx - 2048) * 256 + t) * 4;
        float4 v = *(const float4*)(ys + i);
        f16x4 o;
        o[0] = (_Float16)v.x; o[1] = (_Float16)v.y;
        o[2] = (_Float16)v.z; o[3] = (_Float16)v.w;
        *(f16x4*)(vb + i) = o;
    }
}

// Barrier-free, LDS-free 32x32x16 flash attention.
// R7's counter ledger: 25% matrix + 9% VALU + ~65% stall, with the 2 waves/SIMD
// phase-locked by the per-iter barrier -> every ds_read/L2 latency stalls both
// waves. Fix: no LDS, no barriers, no manual waitcnt. K fragments are read
// DIRECTLY from L2 (kt[b] is XCD-resident; the A-frag read of kt[m][c] is
// contiguous 16B/lane, rows fully line-used). Each wave is an independent
// 32-n flash attention; waves drift out of phase so one wave's MFMA covers the
// other's memory latency, and the compiler pipelines freely.
// Wave w (256-thread block, grid 512, 2 blocks/CU): ns=w&1 (32 n), ch=w>>1
// (128 c). QK^T redundant across the ch pair (price of wave-local softmax);
// P packed into PV B-frags in registers via permlane32_swap (R6/R7-verified).
__global__ __launch_bounds__(256, 2) void kAttn(const float* __restrict__ h,
                                                const _Float16* __restrict__ kt,
                                                const _Float16* __restrict__ vb,
                                                float* __restrict__ out) {
    const int t = threadIdx.x;
    const int w = t >> 6, lane = t & 63, hh = lane >> 5, l31 = lane & 31;
    const int b = blockIdx.x & 7;          // batch -> XCD (kt[b]+vb[b] L2-resident)
    const int n0 = (blockIdx.x >> 3) * NT;
    const int ns = w & 1, ch = w >> 1;

    const _Float16* srcK = kt + (size_t)b * M_ * C_;   // [m][c]
    const _Float16* srcV = vb + (size_t)b * C_ * M_;   // [c][m]

    // ---- Q fragments (B-operand): n = n0+ns*32+l31 ; k = ks*16+hh*8+i -> c ----
    f16x8 qf[16];
    {
        const float* hq = h + (size_t)b * C_ * N_ + n0 + ns * 32 + l31;
#pragma unroll
        for (int ks = 0; ks < 16; ks++) {
            f16x8 q;
#pragma unroll
            for (int i = 0; i < 8; i++)
                q[i] = (_Float16)hq[(size_t)(ks * 16 + hh * 8 + i) * N_];
            qf[ks] = q;
        }
    }

    f32x16 o[4];
#pragma unroll
    for (int cq = 0; cq < 4; cq++)
#pragma unroll
        for (int r = 0; r < 16; r++) o[cq][r] = 0.f;

    float mst = -3.0e38f, lp = 0.f;

    // per-lane row bases (halves)
    const _Float16* kRow0 = srcK + (size_t)(l31) * C_ + hh * 8;        // m-block 0
    const _Float16* kRow1 = srcK + (size_t)(32 + l31) * C_ + hh * 8;   // m-block 1
    const _Float16* vRow0 = srcV + (size_t)(ch * 128 +  0 + l31) * M_ + hh * 8;
    const _Float16* vRow1 = srcV + (size_t)(ch * 128 + 32 + l31) * M_ + hh * 8;
    const _Float16* vRow2 = srcV + (size_t)(ch * 128 + 64 + l31) * M_ + hh * 8;
    const _Float16* vRow3 = srcV + (size_t)(ch * 128 + 96 + l31) * M_ + hh * 8;

    for (int it = 0; it < M_ / MT; it++) {
        const int m0i = it * MT;
        const size_t kOff = (size_t)m0i * C_;

        // ---- V first half (cq 0,1): issued early, consumed at PV ----
        f16x8 vA0[4], vA1[4];
#pragma unroll
        for (int ks = 0; ks < 4; ks++) {
            vA0[ks] = *(const f16x8*)(vRow0 + m0i + ks * 16);
            vA1[ks] = *(const f16x8*)(vRow1 + m0i + ks * 16);
        }

        // ---- S^T = K·Q^T, K fragments streamed straight from L2 ----
        // A-frag: row = l31 -> m = m0i + mh*32 + l31 ; k = ks*16+hh*8+i -> c
        f32x16 sm0, sm1;
#pragma unroll
        for (int r = 0; r < 16; r++) { sm0[r] = 0.f; sm1[r] = 0.f; }
        __builtin_amdgcn_s_setprio(1);
#pragma unroll
        for (int ks = 0; ks < 16; ks++) {
            f16x8 a0 = *(const f16x8*)(kRow0 + kOff + ks * 16);
            sm0 = __builtin_amdgcn_mfma_f32_32x32x16_f16(a0, qf[ks], sm0, 0, 0, 0);
            f16x8 a1 = *(const f16x8*)(kRow1 + kOff + ks * 16);
            sm1 = __builtin_amdgcn_mfma_f32_32x32x16_f16(a1, qf[ks], sm1, 0, 0, 0);
        }
        __builtin_amdgcn_s_setprio(0);

        // ---- in-register online softmax (lane pair l/l^32 holds all 64 m) ----
        float tm[8];
#pragma unroll
        for (int j = 0; j < 8; j++)
            tm[j] = fmaxf(fmaxf(sm0[j], sm0[j + 8]), fmaxf(sm1[j], sm1[j + 8]));
#pragma unroll
        for (int j = 0; j < 4; j++) tm[j] = fmaxf(tm[j], tm[j + 4]);
        float rowmax = fmaxf(fmaxf(tm[0], tm[1]), fmaxf(tm[2], tm[3]));
        rowmax = fmaxf(rowmax, __shfl_xor(rowmax, 32, 64));
        float al = 1.0f;
        if (rowmax > mst) { al = exp2f((mst - rowmax) * L2E); mst = rowmax; }
        const float mb = mst * L2E;
#pragma unroll
        for (int r = 0; r < 16; r++) {
            sm0[r] = exp2f(sm0[r] * L2E - mb);
            sm1[r] = exp2f(sm1[r] * L2E - mb);
        }
        float tp[8];
#pragma unroll
        for (int j = 0; j < 8; j++)
            tp[j] = (sm0[j] + sm0[j + 8]) + (sm1[j] + sm1[j + 8]);
#pragma unroll
        for (int j = 0; j < 4; j++) tp[j] += tp[j + 4];
        float ps = (tp[0] + tp[1]) + (tp[2] + tp[3]);
        ps += __shfl_xor(ps, 32, 64);
        lp = lp * al + ps;

        if (al != 1.0f) {
#pragma unroll
            for (int cq = 0; cq < 4; cq++)
#pragma unroll
                for (int r = 0; r < 16; r++) o[cq][r] *= al;
        }

        // ---- pack P -> PV B-frags in registers (verified R6/R7); sm dies here ----
        f16x8 pfr0, pfr1, pfr2, pfr3;
        {
            unsigned pk[8];
#pragma unroll
            for (int j = 0; j < 8; j++) {
                f16x2 pr;
                pr[0] = (_Float16)sm0[2 * j];
                pr[1] = (_Float16)sm0[2 * j + 1];
                pk[j] = __builtin_bit_cast(unsigned, pr);
            }
            plswap(pk[0], pk[2]);
            plswap(pk[1], pk[3]);
            plswap(pk[4], pk[6]);
            plswap(pk[5], pk[7]);
            u32x4 t0, t1;
            t0[0] = pk[0]; t0[1] = pk[1]; t0[2] = pk[2]; t0[3] = pk[3];
            t1[0] = pk[4]; t1[1] = pk[5]; t1[2] = pk[6]; t1[3] = pk[7];
            pfr0 = __builtin_bit_cast(f16x8, t0);
            pfr1 = __builtin_bit_cast(f16x8, t1);
        }
        {
            unsigned pk[8];
#pragma unroll
            for (int j = 0; j < 8; j++) {
                f16x2 pr;
                pr[0] = (_Float16)sm1[2 * j];
                pr[1] = (_Float16)sm1[2 * j + 1];
                pk[j] = __builtin_bit_cast(unsigned, pr);
            }
            plswap(pk[0], pk[2]);
            plswap(pk[1], pk[3]);
            plswap(pk[4], pk[6]);
            plswap(pk[5], pk[7]);
            u32x4 t0, t1;
            t0[0] = pk[0]; t0[1] = pk[1]; t0[2] = pk[2]; t0[3] = pk[3];
            t1[0] = pk[4]; t1[1] = pk[5]; t1[2] = pk[6]; t1[3] = pk[7];
            pfr2 = __builtin_bit_cast(f16x8, t0);
            pfr3 = __builtin_bit_cast(f16x8, t1);
        }

        // ---- V second half (cq 2,3): latency hidden under PV first half ----
        f16x8 vB2[4], vB3[4];
#pragma unroll
        for (int ks = 0; ks < 4; ks++) {
            vB2[ks] = *(const f16x8*)(vRow2 + m0i + ks * 16);
            vB3[ks] = *(const f16x8*)(vRow3 + m0i + ks * 16);
        }

        // ---- O += V·P^T (pure register MFMA) ----
        __builtin_amdgcn_s_setprio(1);
        o[0] = __builtin_amdgcn_mfma_f32_32x32x16_f16(vA0[0], pfr0, o[0], 0, 0, 0);
        o[1] = __builtin_amdgcn_mfma_f32_32x32x16_f16(vA1[0], pfr0, o[1], 0, 0, 0);
        o[0] = __builtin_amdgcn_mfma_f32_32x32x16_f16(vA0[1], pfr1, o[0], 0, 0, 0);
        o[1] = __builtin_amdgcn_mfma_f32_32x32x16_f16(vA1[1], pfr1, o[1], 0, 0, 0);
        o[0] = __builtin_amdgcn_mfma_f32_32x32x16_f16(vA0[2], pfr2, o[0], 0, 0, 0);
        o[1] = __builtin_amdgcn_mfma_f32_32x32x16_f16(vA1[2], pfr2, o[1], 0, 0, 0);
        o[0] = __builtin_amdgcn_mfma_f32_32x32x16_f16(vA0[3], pfr3, o[0], 0, 0, 0);
        o[1] = __builtin_amdgcn_mfma_f32_32x32x16_f16(vA1[3], pfr3, o[1], 0, 0, 0);
        o[2] = __builtin_amdgcn_mfma_f32_32x32x16_f16(vB2[0], pfr0, o[2], 0, 0, 0);
        o[3] = __builtin_amdgcn_mfma_f32_32x32x16_f16(vB3[0], pfr0, o[3], 0, 0, 0);
        o[2] = __builtin_amdgcn_mfma_f32_32x32x16_f16(vB2[1], pfr1, o[2], 0, 0, 0);
        o[3] = __builtin_amdgcn_mfma_f32_32x32x16_f16(vB3[1], pfr1, o[3], 0, 0, 0);
        o[2] = __builtin_amdgcn_mfma_f32_32x32x16_f16(vB2[2], pfr2, o[2], 0, 0, 0);
        o[3] = __builtin_amdgcn_mfma_f32_32x32x16_f16(vB3[2], pfr2, o[3], 0, 0, 0);
        o[2] = __builtin_amdgcn_mfma_f32_32x32x16_f16(vB2[3], pfr3, o[2], 0, 0, 0);
        o[3] = __builtin_amdgcn_mfma_f32_32x32x16_f16(vB3[3], pfr3, o[3], 0, 0, 0);
        __builtin_amdgcn_s_setprio(0);
    }

    // ---- epilogue: fully lane-local normalize + store ----
    const float linv = 1.0f / lp;
#pragma unroll
    for (int cq = 0; cq < 4; cq++)
#pragma unroll
        for (int r = 0; r < 16; r++) {
            int c = ch * 128 + cq * 32 + (r & 3) + 8 * (r >> 2) + 4 * hh;
            out[((size_t)(b * C_ + c)) * N_ + n0 + ns * 32 + l31] = o[cq][r] * linv;
        }
}

extern "C" void kernel_launch(void* const* d_in, const int* in_sizes, int n_in,
                              void* d_out, int out_size, void* d_ws, size_t ws_size,
                              hipStream_t stream) {
    const float* h  = (const float*)d_in[0];
    const float* xs = (const float*)d_in[1];
    const float* ys = (const float*)d_in[2];
    float* out = (float*)d_out;

    _Float16* kt  = (_Float16*)d_ws;                    // [B,M,C] fp16: 16 MB
    _Float16* vbb = kt + (size_t)B_ * M_ * C_;          // [B,C,M] fp16: 16 MB

    kPre<<<dim3(2048 + 8192), 256, 0, stream>>>(xs, ys, kt, vbb);
    kAttn<<<dim3(B_ * (N_ / NT)), 256, 0, stream>>>(h, kt, vbb, out);
}